// Round 4
// baseline (214.541 us; speedup 1.0000x reference)
//
#include <hip/hip_runtime.h>

#define BATCH   8192
#define FEAT    256
#define NCLASS  100000
#define EPS_C   1e-6f

#define NC_ELEMS (NCLASS * FEAT)          // 25,600,000
#define FUSED_BLOCKS 2048                 // persistent-ish grid, 4 waves/block
#define WAVES_TOTAL  (FUSED_BLOCKS * 4)   // 8192 waves
#define ROWS_PER_WAVE 13                  // ceil(100000 / 8192)

// Tiny: build per-class linked lists. head memset to -1 beforehand.
__global__ void build_kernel(const int* __restrict__ target,
                             int* __restrict__ head,
                             int* __restrict__ next) {
    int b = blockIdx.x * blockDim.x + threadIdx.x;
    if (b < BATCH) next[b] = atomicExch(&head[target[b]], b);
}

// Each wave owns a contiguous chunk of ROWS_PER_WAVE center rows.
// Heads for the whole chunk are preloaded in ONE coalesced load (lane l
// holds head[r0+l]) and broadcast per-row via __shfl. Row loads are
// software-pipelined depth-2 so ~2KB of reads stay in flight per wave.
// Output shift (+1 float; out[0]=loss slot) handled in-register exactly as
// before: lane l>=1 stores aligned float4 {shfl_up(n.w), n.x, n.y, n.z},
// lane 0 stores 3 scalars, lane 63 stores the right-boundary element.
// No LDS, no barriers, no cross-wave communication.
__global__ void fused_kernel(const float* __restrict__ centers,
                             const float* __restrict__ features,
                             const int* __restrict__ head,
                             const int* __restrict__ next,
                             float* __restrict__ partials,
                             float* __restrict__ out /* d_out base */) {
    int w = threadIdx.x >> 6;             // wave 0..3
    int l = threadIdx.x & 63;             // lane
    int gw = blockIdx.x * 4 + w;          // global wave id
    int r0 = gw * ROWS_PER_WAVE;
    if (r0 >= NCLASS) return;
    int nrows = NCLASS - r0;
    if (nrows > ROWS_PER_WAVE) nrows = ROWS_PER_WAVE;

    // one coalesced head preload for the whole chunk
    int myhead = (l < nrows) ? head[r0 + l] : -1;

    const float4* cbase = (const float4*)centers;   // row r, lane l: cbase[r*64+l]

    // depth-2 pipelined row loads
    float4 f0 = cbase[(size_t)r0 * 64 + l];
    float4 f1 = (nrows > 1) ? cbase[(size_t)(r0 + 1) * 64 + l] : f0;

    for (int j = 0; j < nrows; ++j) {
        float4 c4 = f0;
        f0 = f1;
        if (j + 2 < nrows) f1 = cbase[(size_t)(r0 + j + 2) * 64 + l];

        int r = r0 + j;
        int h = __shfl(myhead, j, 64);    // wave-uniform
        float4 n4 = c4;
        if (h != -1) {
            float4 sumf = {0.f, 0.f, 0.f, 0.f};
            int n = 0;
            for (int s = h; s != -1; s = next[s]) {
                float4 f4 = ((const float4*)(features + (size_t)s * FEAT))[l];
                sumf.x += f4.x; sumf.y += f4.y; sumf.z += f4.z; sumf.w += f4.w;
                float dx = c4.x - f4.x, dy = c4.y - f4.y;
                float dz = c4.z - f4.z, dw = c4.w - f4.w;
                float sq = dx*dx + dy*dy + dz*dz + dw*dw;
                #pragma unroll
                for (int off = 32; off > 0; off >>= 1)
                    sq += __shfl_down(sq, off, 64);
                if (l == 0) partials[s] = sq;   // each sample is in exactly one list
                n++;
            }
            float nf = (float)n;
            float inv = 1.0f / (nf + EPS_C);
            // new = c - (n*c - sum_f)/(n+eps)
            n4.x = c4.x - (nf * c4.x - sumf.x) * inv;
            n4.y = c4.y - (nf * c4.y - sumf.y) * inv;
            n4.z = c4.z - (nf * c4.z - sumf.z) * inv;
            n4.w = c4.w - (nf * c4.w - sumf.w) * inv;
        }

        // shifted store, in-register
        float pw = __shfl_up(n4.w, 1, 64);        // new nc[r*256 + 4l - 1], l>=1
        if (l > 0) {
            float4 ov = {pw, n4.x, n4.y, n4.z};
            ((float4*)out)[(size_t)r * 64 + l] = ov;
        } else {
            size_t base = (size_t)r * FEAT;       // out[base] owned by row r-1
            out[base + 1] = n4.x;
            out[base + 2] = n4.y;
            out[base + 3] = n4.z;
        }
        if (l == 63) {
            // out[(r+1)*256] = new nc[(r+1)*256 - 1]; for r==NCLASS-1 this is
            // exactly the tail element out[NC_ELEMS].
            out[(size_t)(r + 1) * FEAT] = n4.w;
        }
    }
}

__global__ void finalize_kernel(const float* __restrict__ partials,
                                float* __restrict__ out0) {
    float s = 0.0f;
    for (int i = threadIdx.x; i < BATCH; i += 256) s += partials[i];
    #pragma unroll
    for (int off = 32; off > 0; off >>= 1) s += __shfl_down(s, off, 64);
    __shared__ float red[4];
    int wave = threadIdx.x >> 6;
    int lane = threadIdx.x & 63;
    if (lane == 0) red[wave] = s;
    __syncthreads();
    if (threadIdx.x == 0) {
        out0[0] = (red[0] + red[1] + red[2] + red[3]) / (float)(BATCH * FEAT);
    }
}

extern "C" void kernel_launch(void* const* d_in, const int* in_sizes, int n_in,
                              void* d_out, int out_size, void* d_ws, size_t ws_size,
                              hipStream_t stream) {
    const float* features = (const float*)d_in[0];
    const int*   target   = (const int*)d_in[1];
    const float* centers  = (const float*)d_in[2];
    float* out = (float*)d_out;

    int*   head     = (int*)d_ws;                                  // 100000 ints
    int*   next     = head + NCLASS;                               // 8192 ints
    float* partials = (float*)(next + BATCH);                      // 8192 floats

    hipMemsetAsync(head, 0xFF, NCLASS * sizeof(int), stream);      // head = -1
    build_kernel<<<(BATCH + 255) / 256, 256, 0, stream>>>(target, head, next);
    fused_kernel<<<FUSED_BLOCKS, 256, 0, stream>>>(centers, features, head, next,
                                                   partials, out);
    finalize_kernel<<<1, 256, 0, stream>>>(partials, out);
}

// Round 5
// 210.232 us; speedup vs baseline: 1.0205x; 1.0205x over previous
//
#include <hip/hip_runtime.h>

#define BATCH   8192
#define FEAT    256
#define NCLASS  100000
#define EPS_C   1e-6f

#define NC_ELEMS (NCLASS * FEAT)          // 25,600,000 floats
#define NVEC     (NC_ELEMS / 4)           // 6,400,000 float4 slots
#define CHUNK    1024                     // float4 slots per block-chunk (4/thread)
#define NCHUNK   (NVEC / CHUNK)           // 6250, exact
#define COPY_GRID 2048                    // 8 blocks/CU, grid-stride over chunks

// 16B vector with 4-byte alignment: lets us load the shifted window
// nc[4g-1 .. 4g+2] as ONE global_load_dwordx4 (gfx9+ supports dword-aligned
// multi-dword access). GCC/Clang: aligned attr on a typedef may lower alignment.
typedef float float4a __attribute__((vector_size(16)));
typedef float4a float4u __attribute__((aligned(4)));

// Tiny: build per-class linked lists. head memset to -1 beforehand.
__global__ void build_kernel(const int* __restrict__ target,
                             int* __restrict__ head,
                             int* __restrict__ next) {
    int b = blockIdx.x * blockDim.x + threadIdx.x;
    if (b < BATCH) next[b] = atomicExch(&head[target[b]], b);
}

// Pure shifted copy: out[k] = centers[k-1] for all k >= 1 (out[0] = loss slot,
// written by finalize). Shift is handled ON THE READ SIDE with unaligned 16B
// loads, so there are no cross-lane ops, no LDS, no divergent seams — just
// 4 independent loads then 4 aligned stores per thread per chunk (4KB of reads
// in flight per wave). Touched rows are stale here; update_kernel (stream-
// ordered after) overwrites them with final values.
__global__ void copy_kernel(const float* __restrict__ centers,
                            float* __restrict__ out) {
    int t = threadIdx.x;
    for (int chunk = blockIdx.x; chunk < NCHUNK; chunk += gridDim.x) {
        size_t base = (size_t)chunk * CHUNK + t;     // this thread's first float4 slot
        const float* s = centers + 4 * base - 1;     // 4B-aligned window start
        float4u v0, v1, v2, v3;
        if (base != 0) {
            v0 = *(const float4u*)s;
        } else {
            v0 = (float4u){0.f, centers[0], centers[1], centers[2]};  // slot 0
        }
        v1 = *(const float4u*)(s + 1024);
        v2 = *(const float4u*)(s + 2048);
        v3 = *(const float4u*)(s + 3072);
        float* d = out + 4 * base;                   // 16B-aligned
        *(float4a*)(d)        = v0;
        *(float4a*)(d + 1024) = v1;
        *(float4a*)(d + 2048) = v2;
        *(float4a*)(d + 3072) = v3;
    }
    // tail element out[NC_ELEMS] = old last element (update overwrites if touched)
    if (blockIdx.x == 0 && t == 0) out[NC_ELEMS] = centers[NC_ELEMS - 1];
}

// One wave per SAMPLE; the wave whose sample is the list head owns the class:
// walks the list, writes per-sample loss partials, and overwrites the full
// shifted row [r*256+1 .. (r+1)*256] in out with final values.
__global__ void update_kernel(const float* __restrict__ centers,
                              const float* __restrict__ features,
                              const int* __restrict__ target,
                              const int* __restrict__ head,
                              const int* __restrict__ next,
                              float* __restrict__ partials,
                              float* __restrict__ out) {
    int wv = (blockIdx.x * blockDim.x + threadIdx.x) >> 6;   // sample id 0..8191
    int l  = threadIdx.x & 63;
    int r  = target[wv];
    if (head[r] != wv) return;            // only the head sample's wave proceeds

    const float4 c4 = ((const float4*)(centers + (size_t)r * FEAT))[l];
    float4 sumf = {0.f, 0.f, 0.f, 0.f};
    int n = 0;
    for (int s = wv; s != -1; s = next[s]) {
        float4 f4 = ((const float4*)(features + (size_t)s * FEAT))[l];
        sumf.x += f4.x; sumf.y += f4.y; sumf.z += f4.z; sumf.w += f4.w;
        float dx = c4.x - f4.x, dy = c4.y - f4.y;
        float dz = c4.z - f4.z, dw = c4.w - f4.w;
        float sq = dx*dx + dy*dy + dz*dz + dw*dw;
        #pragma unroll
        for (int off = 32; off > 0; off >>= 1) sq += __shfl_down(sq, off, 64);
        if (l == 0) partials[s] = sq;     // each sample is in exactly one list
        n++;
    }
    float nf  = (float)n;
    float inv = 1.0f / (nf + EPS_C);
    // new = c - (n*c - sum_f)/(n+eps)
    float nx = c4.x - (nf * c4.x - sumf.x) * inv;
    float ny = c4.y - (nf * c4.y - sumf.y) * inv;
    float nz = c4.z - (nf * c4.z - sumf.z) * inv;
    float nw = c4.w - (nf * c4.w - sumf.w) * inv;

    // shifted row overwrite: one unaligned 16B store per lane covers
    // out[r*256+1+4l .. r*256+4+4l]; lane 63 covers the right boundary.
    *(float4u*)(out + 1 + (size_t)r * FEAT + 4 * l) = (float4u){nx, ny, nz, nw};
}

__global__ void finalize_kernel(const float* __restrict__ partials,
                                float* __restrict__ out0) {
    float s = 0.0f;
    for (int i = threadIdx.x; i < BATCH; i += 256) s += partials[i];
    #pragma unroll
    for (int off = 32; off > 0; off >>= 1) s += __shfl_down(s, off, 64);
    __shared__ float red[4];
    int wave = threadIdx.x >> 6;
    int lane = threadIdx.x & 63;
    if (lane == 0) red[wave] = s;
    __syncthreads();
    if (threadIdx.x == 0) {
        out0[0] = (red[0] + red[1] + red[2] + red[3]) / (float)(BATCH * FEAT);
    }
}

extern "C" void kernel_launch(void* const* d_in, const int* in_sizes, int n_in,
                              void* d_out, int out_size, void* d_ws, size_t ws_size,
                              hipStream_t stream) {
    const float* features = (const float*)d_in[0];
    const int*   target   = (const int*)d_in[1];
    const float* centers  = (const float*)d_in[2];
    float* out = (float*)d_out;

    int*   head     = (int*)d_ws;                                  // 100000 ints
    int*   next     = head + NCLASS;                               // 8192 ints
    float* partials = (float*)(next + BATCH);                      // 8192 floats

    hipMemsetAsync(head, 0xFF, NCLASS * sizeof(int), stream);      // head = -1
    build_kernel<<<(BATCH + 255) / 256, 256, 0, stream>>>(target, head, next);
    copy_kernel<<<COPY_GRID, 256, 0, stream>>>(centers, out);
    update_kernel<<<BATCH / 4, 256, 0, stream>>>(centers, features, target,
                                                 head, next, partials, out);
    finalize_kernel<<<1, 256, 0, stream>>>(partials, out);
}

// Round 6
// 209.048 us; speedup vs baseline: 1.0263x; 1.0057x over previous
//
#include <hip/hip_runtime.h>

#define BATCH   8192
#define FEAT    256
#define NCLASS  100000
#define EPS_C   1e-6f

#define NC_ELEMS (NCLASS * FEAT)          // 25,600,000 floats
#define ROWS_PER_WAVE 4
#define ROWS_PER_BLOCK 16                 // 4 waves * 4 rows
#define FUSED_BLOCKS (NCLASS / ROWS_PER_BLOCK)   // 6250, exact

// 16B vector with 4B alignment for the shifted (off-by-one-float) stores.
typedef float float4a __attribute__((vector_size(16)));
typedef float4a float4u __attribute__((aligned(4)));

// Tiny: build per-class linked lists. head memset to -1 beforehand.
__global__ void build_kernel(const int* __restrict__ target,
                             int* __restrict__ head,
                             int* __restrict__ next) {
    int b = blockIdx.x * blockDim.x + threadIdx.x;
    if (b < BATCH) next[b] = atomicExch(&head[target[b]], b);
}

// Each wave owns 4 consecutive center rows. All 4 row-loads (aligned float4,
// 1KB each) + 4 head flags are issued up front -> 4KB of independent reads in
// flight per wave (fixes R3's one-row-in-flight latency bound). Per row:
// untouched -> n4 = c4; touched -> walk the class list (computes per-sample
// loss partials via shfl reduce). The +1-float output shift is done with ONE
// unaligned 16B store per lane: lane l writes out[r*256+1+4l .. r*256+4+4l].
// Per-row coverage [r*256+1, (r+1)*256] => right boundary and the tail element
// out[NC_ELEMS] are covered naturally; every element written exactly once.
// No LDS, no shfl on the store path, no special lanes. out[0] = finalize.
__global__ void fused_kernel(const float* __restrict__ centers,
                             const float* __restrict__ features,
                             const int* __restrict__ head,
                             const int* __restrict__ next,
                             float* __restrict__ partials,
                             float* __restrict__ out /* d_out base */) {
    int w = threadIdx.x >> 6;             // wave 0..3
    int l = threadIdx.x & 63;             // lane
    int rb = blockIdx.x * ROWS_PER_BLOCK + w * ROWS_PER_WAVE;

    const float4* cb = (const float4*)centers;
    float4 c0 = cb[(size_t)(rb + 0) * 64 + l];
    float4 c1 = cb[(size_t)(rb + 1) * 64 + l];
    float4 c2 = cb[(size_t)(rb + 2) * 64 + l];
    float4 c3 = cb[(size_t)(rb + 3) * 64 + l];
    int h0 = head[rb + 0];
    int h1 = head[rb + 1];
    int h2 = head[rb + 2];
    int h3 = head[rb + 3];

    float4 c[4] = {c0, c1, c2, c3};
    int    h[4] = {h0, h1, h2, h3};

    #pragma unroll
    for (int j = 0; j < ROWS_PER_WAVE; ++j) {
        int r = rb + j;
        float4 c4 = c[j];
        float4 n4 = c4;
        if (h[j] != -1) {                 // wave-uniform branch, ~7.7% of rows
            float4 sumf = {0.f, 0.f, 0.f, 0.f};
            int n = 0;
            for (int s = h[j]; s != -1; s = next[s]) {
                float4 f4 = ((const float4*)(features + (size_t)s * FEAT))[l];
                sumf.x += f4.x; sumf.y += f4.y; sumf.z += f4.z; sumf.w += f4.w;
                float dx = c4.x - f4.x, dy = c4.y - f4.y;
                float dz = c4.z - f4.z, dw = c4.w - f4.w;
                float sq = dx*dx + dy*dy + dz*dz + dw*dw;
                #pragma unroll
                for (int off = 32; off > 0; off >>= 1)
                    sq += __shfl_down(sq, off, 64);
                if (l == 0) partials[s] = sq;   // each sample in exactly one list
                n++;
            }
            float nf = (float)n;
            float inv = 1.0f / (nf + EPS_C);
            // new = c - (n*c - sum_f)/(n+eps)
            n4.x = c4.x - (nf * c4.x - sumf.x) * inv;
            n4.y = c4.y - (nf * c4.y - sumf.y) * inv;
            n4.z = c4.z - (nf * c4.z - sumf.z) * inv;
            n4.w = c4.w - (nf * c4.w - sumf.w) * inv;
        }
        // shifted store: one unaligned 16B store per lane, no cross-lane ops
        *(float4u*)(out + 1 + (size_t)r * FEAT + 4 * l) =
            (float4u){n4.x, n4.y, n4.z, n4.w};
    }
}

__global__ void finalize_kernel(const float* __restrict__ partials,
                                float* __restrict__ out0) {
    float s = 0.0f;
    for (int i = threadIdx.x; i < BATCH; i += 256) s += partials[i];
    #pragma unroll
    for (int off = 32; off > 0; off >>= 1) s += __shfl_down(s, off, 64);
    __shared__ float red[4];
    int wave = threadIdx.x >> 6;
    int lane = threadIdx.x & 63;
    if (lane == 0) red[wave] = s;
    __syncthreads();
    if (threadIdx.x == 0) {
        out0[0] = (red[0] + red[1] + red[2] + red[3]) / (float)(BATCH * FEAT);
    }
}

extern "C" void kernel_launch(void* const* d_in, const int* in_sizes, int n_in,
                              void* d_out, int out_size, void* d_ws, size_t ws_size,
                              hipStream_t stream) {
    const float* features = (const float*)d_in[0];
    const int*   target   = (const int*)d_in[1];
    const float* centers  = (const float*)d_in[2];
    float* out = (float*)d_out;

    int*   head     = (int*)d_ws;                                  // 100000 ints
    int*   next     = head + NCLASS;                               // 8192 ints
    float* partials = (float*)(next + BATCH);                      // 8192 floats

    hipMemsetAsync(head, 0xFF, NCLASS * sizeof(int), stream);      // head = -1
    build_kernel<<<(BATCH + 255) / 256, 256, 0, stream>>>(target, head, next);
    fused_kernel<<<FUSED_BLOCKS, 256, 0, stream>>>(centers, features, head, next,
                                                   partials, out);
    finalize_kernel<<<1, 256, 0, stream>>>(partials, out);
}

// Round 7
// 199.164 us; speedup vs baseline: 1.0772x; 1.0496x over previous
//
#include <hip/hip_runtime.h>

#define BATCH   8192
#define FEAT    256
#define NCLASS  100000
#define EPS_C   1e-6f

#define NC_ELEMS (NCLASS * FEAT)          // 25,600,000 floats
#define FUSED_BLOCKS (NCLASS / 4)         // 25,000 blocks; 4 rows/block, 1/wave

// 16B vector with 4B alignment (only used on the rare touched-row store path).
typedef float float4a __attribute__((vector_size(16)));
typedef float4a float4u __attribute__((aligned(4)));

// Tiny: build per-class linked lists. head memset to -1 beforehand.
__global__ void build_kernel(const int* __restrict__ target,
                             int* __restrict__ head,
                             int* __restrict__ next) {
    int b = blockIdx.x * blockDim.x + threadIdx.x;
    if (b < BATCH) next[b] = atomicExch(&head[target[b]], b);
}

// One wave per center row. Output slot g covers out[4g..4g+3] =
// new_centers[4g-1..4g+2] (out[0] = loss slot, finalize overwrites).
//
// UNTOUCHED row (99.2% of rows; fully uniform, branchless, aligned):
//   cur = cb[g], prv = cb[g-1]  (adjacent -> prv is an L1/L2 hit; HBM FETCH
//   unchanged), store aligned float4 {prv.w, cur.x, cur.y, cur.z}.
//   Lane 0's prv.w is the PREVIOUS row's last element — valid iff that row is
//   untouched; if touched, lane 0 instead stores 3 scalars (out[r*256] is
//   covered by the touched previous wave's store, see below).
//
// TOUCHED row (7.7%, wave-uniform branch): walk the class list (per-sample
//   loss partials via shfl reduce), then one unaligned 16B store per lane
//   covering out[r*256+1 .. (r+1)*256] — the full updated row incl. the next
//   slot's .x element. Lane 0 patches out[r*256] (prev row's last elem) only
//   if the prev row is untouched. Coverage partition is exact: every out
//   element written exactly once across all cases -> no races, no ordering
//   assumptions between waves.
__global__ void fused_kernel(const float* __restrict__ centers,
                             const float* __restrict__ features,
                             const int* __restrict__ head,
                             const int* __restrict__ next,
                             float* __restrict__ partials,
                             float* __restrict__ out /* d_out base */) {
    int w = threadIdx.x >> 6;             // wave 0..3
    int l = threadIdx.x & 63;             // lane
    int r = blockIdx.x * 4 + w;           // center row for this wave
    size_t g = (size_t)r * 64 + l;        // output float4 slot

    const float4* cb = (const float4*)centers;
    float4 cur = cb[g];
    float4 prv = cb[g ? g - 1 : 0];       // g==0 clamp: lands in loss slot anyway
    int h  = head[r];                     // wave-uniform
    int hp = (r > 0) ? head[r - 1] : -1;  // wave-uniform

    if (h == -1) {
        if (l == 0 && hp != -1) {
            // out[r*256] written by touched wave r-1; write only our 3 elems
            size_t base = (size_t)r * FEAT;
            out[base + 1] = cur.x; out[base + 2] = cur.y; out[base + 3] = cur.z;
        } else {
            float4 ov = {prv.w, cur.x, cur.y, cur.z};
            ((float4*)out)[g] = ov;
        }
        if (r == NCLASS - 1 && l == 63) out[NC_ELEMS] = cur.w;   // tail elem
    } else {
        float4 c4 = cur;
        float4 sumf = {0.f, 0.f, 0.f, 0.f};
        int n = 0;
        for (int s = h; s != -1; s = next[s]) {
            float4 f4 = ((const float4*)(features + (size_t)s * FEAT))[l];
            sumf.x += f4.x; sumf.y += f4.y; sumf.z += f4.z; sumf.w += f4.w;
            float dx = c4.x - f4.x, dy = c4.y - f4.y;
            float dz = c4.z - f4.z, dw = c4.w - f4.w;
            float sq = dx*dx + dy*dy + dz*dz + dw*dw;
            #pragma unroll
            for (int off = 32; off > 0; off >>= 1) sq += __shfl_down(sq, off, 64);
            if (l == 0) partials[s] = sq;   // each sample is in exactly one list
            n++;
        }
        float nf  = (float)n;
        float inv = 1.0f / (nf + EPS_C);
        // new = c - (n*c - sum_f)/(n+eps)
        float nx = c4.x - (nf * c4.x - sumf.x) * inv;
        float ny = c4.y - (nf * c4.y - sumf.y) * inv;
        float nz = c4.z - (nf * c4.z - sumf.z) * inv;
        float nw = c4.w - (nf * c4.w - sumf.w) * inv;
        // full updated row, shifted: covers out[r*256+1 .. (r+1)*256]
        *(float4u*)(out + 1 + (size_t)r * FEAT + 4 * l) = (float4u){nx, ny, nz, nw};
        // seam: out[r*256] = prev row's last elem (old) iff prev row untouched
        if (l == 0 && r > 0 && hp == -1) out[(size_t)r * FEAT] = prv.w;
        // r==NCLASS-1: the unaligned store of lane 63 covers out[NC_ELEMS]
    }
}

__global__ void finalize_kernel(const float* __restrict__ partials,
                                float* __restrict__ out0) {
    float s = 0.0f;
    for (int i = threadIdx.x; i < BATCH; i += 256) s += partials[i];
    #pragma unroll
    for (int off = 32; off > 0; off >>= 1) s += __shfl_down(s, off, 64);
    __shared__ float red[4];
    int wave = threadIdx.x >> 6;
    int lane = threadIdx.x & 63;
    if (lane == 0) red[wave] = s;
    __syncthreads();
    if (threadIdx.x == 0) {
        out0[0] = (red[0] + red[1] + red[2] + red[3]) / (float)(BATCH * FEAT);
    }
}

extern "C" void kernel_launch(void* const* d_in, const int* in_sizes, int n_in,
                              void* d_out, int out_size, void* d_ws, size_t ws_size,
                              hipStream_t stream) {
    const float* features = (const float*)d_in[0];
    const int*   target   = (const int*)d_in[1];
    const float* centers  = (const float*)d_in[2];
    float* out = (float*)d_out;

    int*   head     = (int*)d_ws;                                  // 100000 ints
    int*   next     = head + NCLASS;                               // 8192 ints
    float* partials = (float*)(next + BATCH);                      // 8192 floats

    hipMemsetAsync(head, 0xFF, NCLASS * sizeof(int), stream);      // head = -1
    build_kernel<<<(BATCH + 255) / 256, 256, 0, stream>>>(target, head, next);
    fused_kernel<<<FUSED_BLOCKS, 256, 0, stream>>>(centers, features, head, next,
                                                   partials, out);
    finalize_kernel<<<1, 256, 0, stream>>>(partials, out);
}